// Round 7
// baseline (750.182 us; speedup 1.0000x reference)
//
#include <hip/hip_runtime.h>
#include <cstddef>
#include <cstdint>

#define S3 32768  // 32*32*32 spatial positions

typedef short bf16x8 __attribute__((ext_vector_type(8)));   // 8 bf16 in 4 VGPRs
typedef float f32x16 __attribute__((ext_vector_type(16)));

static __device__ inline unsigned short f2bf(float f) {
    unsigned int u = __float_as_uint(f);
    unsigned int r = (u + 0x7FFFu + ((u >> 16) & 1u)) >> 16;  // RNE
    return (unsigned short)r;
}

// --------- weight transpose: wT[tap][icb][c][kb][chunk(=half*32+ln)][8ic] --
// One A-fragment (tap,icb,c,kb) = 64 chunks * 16 B = 1 KB; lane i reads
// chunk i (16B) -> conflict-free ds_read_b128.
template <int IC, int OC>
__global__ __launch_bounds__(256) void wt_transpose(
    const float* __restrict__ w, unsigned short* __restrict__ wT)
{
    int t = blockIdx.x * 256 + threadIdx.x;  // < 125*IC*OC
    int e = t & 7;
    int chunk = (t >> 3) & 63;
    int kb = (t >> 9) & 1;
    int rest = t >> 10;                       // (tap*ICB + icb)*WOC + c
    int c = rest % (OC / 32); rest /= (OC / 32);
    int icb = rest % (IC / 32);
    int tap = rest / (IC / 32);
    int ln = chunk & 31, half = chunk >> 5;
    int oc = c * 32 + ln;
    int ic = icb * 32 + kb * 16 + half * 8 + e;
    wT[t] = f2bf(w[((size_t)oc * IC + ic) * 125 + tap]);
}

// ---------------- x transpose: xb[b][z][y][x][128 ic] bf16 -----------------
__global__ __launch_bounds__(256) void xb_transpose(
    const float* __restrict__ x, unsigned short* __restrict__ xb)
{
    __shared__ float tile[32][133];
    int zy = blockIdx.x, b = blockIdx.y;
    int t = threadIdx.x, xi = t & 31, ich = t >> 5;
#pragma unroll
    for (int k = 0; k < 16; ++k) {
        int ic = k * 8 + ich;
        tile[xi][ic] = x[(size_t)(b * 128 + ic) * S3 + zy * 32 + xi];
    }
    __syncthreads();
#pragma unroll
    for (int k = 0; k < 2; ++k) {
        int u = t + 256 * k;
        int xx = u >> 4, j = u & 15;
        __align__(16) unsigned short tmp[8];
#pragma unroll
        for (int e = 0; e < 8; ++e) tmp[e] = f2bf(tile[xx][j * 8 + e]);
        *(uint4*)(xb + ((size_t)b * S3 + zy * 32 + xx) * 128 + j * 8) =
            *(const uint4*)tmp;
    }
}

// ---------------- attention (row 4 only), writes alpha*att into d_out ------
__global__ __launch_bounds__(256) void attention_kernel(
    const float* __restrict__ x, const float* __restrict__ basis,
    const float* __restrict__ mixer, const float* __restrict__ wq,
    const float* __restrict__ wk, const float* __restrict__ wv,
    const float* __restrict__ alpha_p, float* __restrict__ out)
{
    int t = blockIdx.x * 256 + threadIdx.x;
    int s = t & (S3 - 1);
    int b = t >> 15;

    float tok[32];
#pragma unroll
    for (int c = 0; c < 32; ++c) tok[c] = 0.f;
#pragma unroll
    for (int r = 0; r < 8; ++r) {
        float bv = basis[r * S3 + s];
#pragma unroll
        for (int c = 0; c < 32; ++c) tok[c] += mixer[c * 8 + r] * bv;
    }
    const float* wq4 = wq + 4 * 1024;
    float q[32];
#pragma unroll
    for (int o = 0; o < 32; ++o) {
        float a = 0.f;
#pragma unroll
        for (int c = 0; c < 32; ++c) a += wq4[o * 32 + c] * tok[c];
        q[o] = a;
    }

    const float scale = 0.17677669529663687f;
    float l[5];
#pragma unroll
    for (int j = 0; j < 5; ++j) {
        float xv[32];
        const float* xp = (j < 4) ? (x + ((size_t)b * 128 + j * 32) * S3) : nullptr;
#pragma unroll
        for (int c = 0; c < 32; ++c) xv[c] = (j < 4) ? xp[(size_t)c * S3 + s] : tok[c];
        const float* wkj = wk + j * 1024;
        float acc = 0.f;
#pragma unroll
        for (int o = 0; o < 32; ++o) {
            float kv = 0.f;
#pragma unroll
            for (int c = 0; c < 32; ++c) kv += wkj[o * 32 + c] * xv[c];
            acc += q[o] * kv;
        }
        l[j] = acc * scale;
    }
    float m = l[0];
#pragma unroll
    for (int j = 1; j < 5; ++j) m = fmaxf(m, l[j]);
    float p[5], sum = 0.f;
#pragma unroll
    for (int j = 0; j < 5; ++j) { p[j] = __expf(l[j] - m); sum += p[j]; }
    float inv = alpha_p[0] / sum;

    float ov[32];
#pragma unroll
    for (int o = 0; o < 32; ++o) ov[o] = 0.f;
#pragma unroll
    for (int j = 0; j < 5; ++j) {
        float xv[32];
        const float* xp = (j < 4) ? (x + ((size_t)b * 128 + j * 32) * S3) : nullptr;
#pragma unroll
        for (int c = 0; c < 32; ++c) xv[c] = (j < 4) ? xp[(size_t)c * S3 + s] : tok[c];
        const float* wvj = wv + j * 1024;
        float pj = p[j];
#pragma unroll
        for (int o = 0; o < 32; ++o) {
            float vv = 0.f;
#pragma unroll
            for (int c = 0; c < 32; ++c) vv += wvj[o * 32 + c] * xv[c];
            ov[o] += pj * vv;
        }
    }
#pragma unroll
    for (int o = 0; o < 32; ++o)
        out[((size_t)b * 32 + o) * S3 + s] = ov[o] * inv;
}

// ---------------- implicit-GEMM 5x5x5 conv via MFMA 32x32x16 bf16 ----------
// 512-thread block (8 waves), 1 block/CU. Block tile: OC x (16 y x 32 x) at
// one z. conv1: waves = 2 oc-halves x 4 y-waves, JT=4 rows/wave.
// conv2: 8 y-waves, JT=2. Per window (icb,dz): input (57.6 KB) AND all 100/50
// weight frags (100/50 KB) staged in LDS, register-prefetched during the
// previous window's compute. 2 barriers per window. A and B both from LDS:
// per wave 50 A-reads + 80 brow-reads vs 200 MFMA (conv1) -> MFMA-bound.
// xin: [b][z][y][x][IC] bf16. wT: [tap][icb][c][kb][chunk][8ic] bf16.
template <int IC, int OC, bool WRITE_H>
__global__ __launch_bounds__(512, 2) void conv_mfma(
    const unsigned short* __restrict__ xin, const uint4* __restrict__ wTq,
    const float* __restrict__ bias, unsigned short* __restrict__ hout,
    float* __restrict__ fout)
{
    constexpr int ICB = IC / 32, WOC = OC / 32;
    constexpr int JT = 2 * WOC;           // rows per wave (4 conv1, 2 conv2)
    constexpr int NW = ICB * 5;           // windows
    constexpr int NFRAG = 50 * WOC;       // weight frags per window
    constexpr int NWQ = NFRAG * 64;       // uint4 of weights per window
    constexpr int NIN = 2880;             // uint4 of input per window (20*36*4)
    constexpr int PREI = 6;               // ceil(2880/512)
    constexpr int PREW = (NWQ + 511) / 512;
    __shared__ __align__(16) char lds_in[20 * 36 * 80];   // 57.6 KB
    __shared__ __align__(16) char lds_w[NFRAG * 1024];    // 100/50 KB

    const int tid = threadIdx.x;
    const int wave = tid >> 6, lane = tid & 63;
    const int ln = lane & 31, half = lane >> 5;
    const int ochalf = (WOC == 2) ? (wave >> 2) : 0;
    const int wy = (WOC == 2) ? (wave & 3) : wave;   // y-wave index
    const int z = blockIdx.x, ybl = blockIdx.y, b = blockIdx.z;
    const int y0 = ybl * 16;

    f32x16 acc[JT];
#pragma unroll
    for (int j = 0; j < JT; ++j)
#pragma unroll
        for (int e = 0; e < 16; ++e) acc[j][e] = 0.f;

    uint4 prei[PREI], prew[PREW];

    auto issue_in = [&](int icb, int dz) {
        int gz = z + dz - 2;
        bool zok = (unsigned)gz < 32u;
#pragma unroll
        for (int k = 0; k < PREI; ++k) {
            int i = tid + 512 * k;
            if (i < NIN) {
                int sub = i & 3, cc = i >> 2;
                int x36 = cc % 36, row = cc / 36;
                int gy = y0 - 2 + row, gx = x36 - 2;
                uint4 v = {0u, 0u, 0u, 0u};
                if (zok && (unsigned)gy < 32u && (unsigned)gx < 32u)
                    v = *(const uint4*)(xin +
                        ((((size_t)b * 32 + gz) * 32 + gy) * 32 + gx) * IC +
                        icb * 32 + sub * 8);
                prei[k] = v;
            }
        }
    };

    auto issue_w = [&](int icb, int dz) {
#pragma unroll
        for (int k = 0; k < PREW; ++k) {
            int i = tid + 512 * k;
            if (i < NWQ) {
                int chunk = i & 63, frag = i >> 6;
                // frag = ((dx*2+kb)*5 + dy)*WOC + c
                int c = frag % WOC;
                int r1 = frag / WOC;
                int dy = r1 % 5;
                int r2 = r1 / 5;
                int kb = r2 & 1, dx = r2 >> 1;
                int tap = (dz * 5 + dy) * 5 + dx;
                prew[k] = wTq[(size_t)((((tap * ICB + icb) * WOC + c) * 2 + kb))
                              * 64 + chunk];
            }
        }
    };

    issue_in(0, 0);
    issue_w(0, 0);

    for (int w = 0; w < NW; ++w) {
        __syncthreads();  // previous window's readers done
#pragma unroll
        for (int k = 0; k < PREI; ++k) {
            int i = tid + 512 * k;
            if (i < NIN) {
                int sub = i & 3, cc = i >> 2;
                int x36 = cc % 36, row = cc / 36;
                *(uint4*)(lds_in + row * 2880 + x36 * 80 + sub * 16) = prei[k];
            }
        }
#pragma unroll
        for (int k = 0; k < PREW; ++k) {
            int i = tid + 512 * k;
            if (i < NWQ) *(uint4*)(lds_w + (size_t)i * 16) = prew[k];
        }
        __syncthreads();  // staging visible

        int nw = w + 1;
        if (nw < NW) {    // prefetch next window during this compute
            issue_in(nw / 5, nw % 5);
            issue_w(nw / 5, nw % 5);
        }

#pragma unroll
        for (int dx = 0; dx < 5; ++dx) {
#pragma unroll
            for (int kb = 0; kb < 2; ++kb) {
                bf16x8 brow[JT + 4];
#pragma unroll
                for (int r = 0; r < JT + 4; ++r)
                    brow[r] = *(const bf16x8*)(lds_in +
                        (JT * wy + r) * 2880 + (ln + dx) * 80 +
                        kb * 32 + half * 16);
#pragma unroll
                for (int dy = 0; dy < 5; ++dy) {
                    bf16x8 a = *(const bf16x8*)(lds_w +
                        (size_t)((((dx * 2 + kb) * 5 + dy) * WOC + ochalf))
                        * 1024 + lane * 16);
#pragma unroll
                    for (int j = 0; j < JT; ++j)
                        acc[j] = __builtin_amdgcn_mfma_f32_32x32x16_bf16(
                            a, brow[dy + j], acc[j], 0, 0, 0);
                }
            }
        }
    }

    __syncthreads();
    if (WRITE_H) {
        // bias + exact GELU, transpose to [x][oc] via LDS scratch (4 rows of
        // 32x x 64oc at a time), store h[b][z][y][x][OC] bf16.
#pragma unroll
        for (int j = 0; j < JT; ++j) {
            char* scr = lds_w + wy * (32 * 144);
#pragma unroll
            for (int r = 0; r < 16; ++r) {
                int ocr = (r & 3) + 8 * (r >> 2) + 4 * half;
                int oc = ochalf * 32 + ocr;
                float v = acc[j][r] + bias[oc];
                v = 0.5f * v * (1.f + erff(v * 0.70710678118654752f));
                *(unsigned short*)(scr + ln * 144 + oc * 2) = f2bf(v);
            }
            __syncthreads();
#pragma unroll
            for (int k = 0; k < 2; ++k) {
                int u = tid + 512 * k;          // < 1024 = 4 rows * 256 uint4
                int wyi = u >> 8, rem = u & 255;
                int xx = rem >> 3, un = rem & 7;
                uint4 v = *(const uint4*)(lds_w + wyi * (32 * 144) +
                                          xx * 144 + un * 16);
                int y = y0 + 4 * wyi + j;
                *(uint4*)(hout + ((((size_t)b * 32 + z) * 32 + y) * 32 + xx)
                          * 64 + un * 8) = v;
            }
            __syncthreads();
        }
    } else {
        // final: bias + attention (already alpha-scaled in fout) added in place
#pragma unroll
        for (int j = 0; j < JT; ++j) {
            int y = y0 + JT * wy + j;
#pragma unroll
            for (int r = 0; r < 16; ++r) {
                int oc = (r & 3) + 8 * (r >> 2) + 4 * half;
                size_t o = ((size_t)b * 32 + oc) * S3 + z * 1024 + y * 32 + ln;
                fout[o] = acc[j][r] + bias[oc] + fout[o];
            }
        }
    }
}

// ---------------------------------------------------------------------------
extern "C" void kernel_launch(void* const* d_in, const int* in_sizes, int n_in,
                              void* d_out, int out_size, void* d_ws, size_t ws_size,
                              hipStream_t stream)
{
    const float* x       = (const float*)d_in[0];
    const float* basis   = (const float*)d_in[1];
    const float* mixer   = (const float*)d_in[2];
    const float* wq      = (const float*)d_in[3];
    const float* wk      = (const float*)d_in[4];
    const float* wv      = (const float*)d_in[5];
    const float* conv1_w = (const float*)d_in[6];
    const float* conv1_b = (const float*)d_in[7];
    const float* conv2_w = (const float*)d_in[8];
    const float* conv2_b = (const float*)d_in[9];
    const float* alpha   = (const float*)d_in[10];
    float* out = (float*)d_out;

    char* wsb = (char*)d_ws;
    unsigned short* xb  = (unsigned short*)wsb;               // 32 MiB
    unsigned short* h   = (unsigned short*)(wsb + 33554432);  // 16 MiB
    unsigned short* wT1 = (unsigned short*)(wsb + 50331648);  // 2 MiB
    unsigned short* wT2 = (unsigned short*)(wsb + 52379648);  // 0.5 MiB

    wt_transpose<128, 64><<<4000, 256, 0, stream>>>(conv1_w, wT1);
    wt_transpose<64, 32><<<1000, 256, 0, stream>>>(conv2_w, wT2);
    xb_transpose<<<dim3(1024, 4), 256, 0, stream>>>(x, xb);

    attention_kernel<<<512, 256, 0, stream>>>(x, basis, mixer, wq, wk, wv,
                                              alpha, out);

    conv_mfma<128, 64, true><<<dim3(32, 2, 4), 512, 0, stream>>>(
        xb, (const uint4*)wT1, conv1_b, h, nullptr);
    conv_mfma<64, 32, false><<<dim3(32, 2, 4), 512, 0, stream>>>(
        h, (const uint4*)wT2, conv2_b, nullptr, out);
}

// Round 8
// 663.323 us; speedup vs baseline: 1.1309x; 1.1309x over previous
//
#include <hip/hip_runtime.h>
#include <cstddef>
#include <cstdint>

#define S3 32768  // 32*32*32 spatial positions

typedef short bf16x8 __attribute__((ext_vector_type(8)));   // 8 bf16 in 4 VGPRs
typedef float f32x16 __attribute__((ext_vector_type(16)));

static __device__ inline unsigned short f2bf(float f) {
    unsigned int u = __float_as_uint(f);
    unsigned int r = (u + 0x7FFFu + ((u >> 16) & 1u)) >> 16;  // RNE
    return (unsigned short)r;
}

// --------- weight transpose: wT[tap][icb][c][kb][chunk(=half*32+ln)][8ic] --
// One A-fragment (tap,icb,c,kb) = 64 chunks * 16 B = 1 KB; lane (ln,half)
// reads chunk half*32+ln.
template <int IC, int OC>
__global__ __launch_bounds__(256) void wt_transpose(
    const float* __restrict__ w, unsigned short* __restrict__ wT)
{
    int t = blockIdx.x * 256 + threadIdx.x;  // < 125*IC*OC
    int e = t & 7;
    int chunk = (t >> 3) & 63;
    int kb = (t >> 9) & 1;
    int rest = t >> 10;                       // (tap*ICB + icb)*WOC + c
    int c = rest % (OC / 32); rest /= (OC / 32);
    int icb = rest % (IC / 32);
    int tap = rest / (IC / 32);
    int ln = chunk & 31, half = chunk >> 5;
    int oc = c * 32 + ln;
    int ic = icb * 32 + kb * 16 + half * 8 + e;
    wT[t] = f2bf(w[((size_t)oc * IC + ic) * 125 + tap]);
}

// ---------------- x transpose: xb[b][z][y][x][128 ic] bf16 -----------------
__global__ __launch_bounds__(256) void xb_transpose(
    const float* __restrict__ x, unsigned short* __restrict__ xb)
{
    __shared__ float tile[32][133];
    int zy = blockIdx.x, b = blockIdx.y;
    int t = threadIdx.x, xi = t & 31, ich = t >> 5;
#pragma unroll
    for (int k = 0; k < 16; ++k) {
        int ic = k * 8 + ich;
        tile[xi][ic] = x[(size_t)(b * 128 + ic) * S3 + zy * 32 + xi];
    }
    __syncthreads();
#pragma unroll
    for (int k = 0; k < 2; ++k) {
        int u = t + 256 * k;
        int xx = u >> 4, j = u & 15;
        __align__(16) unsigned short tmp[8];
#pragma unroll
        for (int e = 0; e < 8; ++e) tmp[e] = f2bf(tile[xx][j * 8 + e]);
        *(uint4*)(xb + ((size_t)b * S3 + zy * 32 + xx) * 128 + j * 8) =
            *(const uint4*)tmp;
    }
}

// ---------------- token = mixer_w @ basis ; q = wq[4] @ token --------------
__global__ __launch_bounds__(256) void token_q_kernel(
    const float* __restrict__ basis, const float* __restrict__ mixer,
    const float* __restrict__ wq, float* __restrict__ token,
    float* __restrict__ qbuf)
{
    int s = blockIdx.x * 256 + threadIdx.x;
    float tok[32];
#pragma unroll
    for (int c = 0; c < 32; ++c) tok[c] = 0.f;
#pragma unroll
    for (int r = 0; r < 8; ++r) {
        float bv = basis[r * S3 + s];
#pragma unroll
        for (int c = 0; c < 32; ++c) tok[c] += mixer[c * 8 + r] * bv;
    }
#pragma unroll
    for (int c = 0; c < 32; ++c) token[c * S3 + s] = tok[c];
    const float* wq4 = wq + 4 * 1024;
#pragma unroll
    for (int o = 0; o < 32; ++o) {
        float a = 0.f;
#pragma unroll
        for (int c = 0; c < 32; ++c) a += wq4[o * 32 + c] * tok[c];
        qbuf[o * S3 + s] = a;
    }
}

// ---------------- attention (row 4 only), writes alpha*att into d_out ------
__global__ __launch_bounds__(256) void attention_kernel(
    const float* __restrict__ x, const float* __restrict__ token,
    const float* __restrict__ qbuf, const float* __restrict__ wk,
    const float* __restrict__ wv, const float* __restrict__ alpha_p,
    float* __restrict__ out)
{
    int t = blockIdx.x * 256 + threadIdx.x;
    int s = t & (S3 - 1);
    int b = t >> 15;

    float q[32];
#pragma unroll
    for (int c = 0; c < 32; ++c) q[c] = qbuf[c * S3 + s];

    const float scale = 0.17677669529663687f;
    float l[5];
#pragma unroll
    for (int j = 0; j < 5; ++j) {
        float xv[32];
        const float* xp = (j < 4) ? (x + ((size_t)b * 128 + j * 32) * S3) : token;
#pragma unroll
        for (int c = 0; c < 32; ++c) xv[c] = xp[(size_t)c * S3 + s];
        const float* wkj = wk + j * 1024;
        float acc = 0.f;
#pragma unroll
        for (int o = 0; o < 32; ++o) {
            float kv = 0.f;
#pragma unroll
            for (int c = 0; c < 32; ++c) kv += wkj[o * 32 + c] * xv[c];
            acc += q[o] * kv;
        }
        l[j] = acc * scale;
    }
    float m = l[0];
#pragma unroll
    for (int j = 1; j < 5; ++j) m = fmaxf(m, l[j]);
    float p[5], sum = 0.f;
#pragma unroll
    for (int j = 0; j < 5; ++j) { p[j] = __expf(l[j] - m); sum += p[j]; }
    float inv = alpha_p[0] / sum;

    float ov[32];
#pragma unroll
    for (int o = 0; o < 32; ++o) ov[o] = 0.f;
#pragma unroll
    for (int j = 0; j < 5; ++j) {
        float xv[32];
        const float* xp = (j < 4) ? (x + ((size_t)b * 128 + j * 32) * S3) : token;
#pragma unroll
        for (int c = 0; c < 32; ++c) xv[c] = xp[(size_t)c * S3 + s];
        const float* wvj = wv + j * 1024;
        float pj = p[j];
#pragma unroll
        for (int o = 0; o < 32; ++o) {
            float vv = 0.f;
#pragma unroll
            for (int c = 0; c < 32; ++c) vv += wvj[o * 32 + c] * xv[c];
            ov[o] += pj * vv;
        }
    }
#pragma unroll
    for (int o = 0; o < 32; ++o)
        out[((size_t)b * 32 + o) * S3 + s] = ov[o] * inv;
}

// ---------------- implicit-GEMM 5x5x5 conv via MFMA 32x32x16 bf16 ----------
// 512-thread block (8 waves), 1 block/CU, block tile OC x (16 y x 32 x) x 1 z.
// conv1: 2 oc-halves x 4 y-waves, JT=4 rows/wave -> 50 A-loads : 200 MFMA
// per wave per window (MFMA-bound). conv2: 8 y-waves, JT=2.
// A (weights) direct from global (L2-resident, per-lane 16B) via register
// double-buffer; input staged in LDS via 6-reg prefetch (never spilled).
// xin: [b][z][y][x][IC] bf16. wT: [tap][icb][c][kb][chunk][8ic] bf16.
template <int IC, int OC, bool WRITE_H>
__global__ __launch_bounds__(512, 2) void conv_mfma(
    const unsigned short* __restrict__ xin, const uint4* __restrict__ wTq,
    const float* __restrict__ bias, unsigned short* __restrict__ hout,
    float* __restrict__ fout)
{
    constexpr int ICB = IC / 32, WOC = OC / 32;
    constexpr int JT = 2 * WOC;        // 4 conv1, 2 conv2
    constexpr int NW = ICB * 5;
    constexpr int NIN = 2880;          // 20 rows * 36 x * 4 chunks
    __shared__ __align__(16) char lds_in[20 * 36 * 80];  // 57.6 KB

    const int tid = threadIdx.x;
    const int wave = tid >> 6, lane = tid & 63;
    const int ln = lane & 31, half = lane >> 5;
    const int ochalf = (WOC == 2) ? (wave >> 2) : 0;
    const int wy = (WOC == 2) ? (wave & 3) : wave;
    const int z = blockIdx.x, ybl = blockIdx.y, b = blockIdx.z;
    const int y0 = ybl * 16;

    const uint4* wTl = wTq + half * 32 + ln;  // lane-fixed chunk offset

    f32x16 acc[JT];
#pragma unroll
    for (int j = 0; j < JT; ++j)
#pragma unroll
        for (int e = 0; e < 16; ++e) acc[j][e] = 0.f;

    uint4 prei[6];  // 2880 uint4 / 512 threads

    auto issue = [&](int icb, int dz) {
        int gz = z + dz - 2;
        bool zok = (unsigned)gz < 32u;
#pragma unroll
        for (int k = 0; k < 6; ++k) {
            int i = tid + 512 * k;
            if (i < NIN) {
                int sub = i & 3, cc = i >> 2;
                int x36 = cc % 36, row = cc / 36;
                int gy = y0 - 2 + row, gx = x36 - 2;
                uint4 v = {0u, 0u, 0u, 0u};
                if (zok && (unsigned)gy < 32u && (unsigned)gx < 32u)
                    v = *(const uint4*)(xin +
                        ((((size_t)b * 32 + gz) * 32 + gy) * 32 + gx) * IC +
                        icb * 32 + sub * 8);
                prei[k] = v;
            }
        }
    };

    bf16x8 bufA[5], bufB[5];

    auto fillA = [&](bool valid, int icb, int dz, int dx, int kb,
                     bf16x8 (&buf)[5]) {
        if (!valid) return;
#pragma unroll
        for (int dy = 0; dy < 5; ++dy) {
            int tap = (dz * 5 + dy) * 5 + dx;
            int f = ((tap * ICB + icb) * WOC + ochalf) * 2 + kb;
            buf[dy] = *(const bf16x8*)(wTl + (size_t)f * 64);
        }
    };

    auto compute = [&](bf16x8 (&cur)[5], int dx, int kb) {
        bf16x8 brow[JT + 4];
#pragma unroll
        for (int r = 0; r < JT + 4; ++r)
            brow[r] = *(const bf16x8*)(lds_in + (JT * wy + r) * 2880 +
                                       (ln + dx) * 80 + kb * 32 + half * 16);
#pragma unroll
        for (int dy = 0; dy < 5; ++dy)
#pragma unroll
            for (int j = 0; j < JT; ++j)
                acc[j] = __builtin_amdgcn_mfma_f32_32x32x16_bf16(
                    cur[dy], brow[dy + j], acc[j], 0, 0, 0);
    };

    issue(0, 0);
    fillA(true, 0, 0, 0, 0, bufA);

    for (int w = 0; w < NW; ++w) {
        int icb = w / 5, dz = w - icb * 5;
        int nw = w + 1;
        int nicb = nw / 5, ndz = nw - nicb * 5;
        bool more = nw < NW;

        __syncthreads();  // previous window's readers done
#pragma unroll
        for (int k = 0; k < 6; ++k) {
            int i = tid + 512 * k;
            if (i < NIN) {
                int sub = i & 3, cc = i >> 2;
                int x36 = cc % 36, row = cc / 36;
                *(uint4*)(lds_in + row * 2880 + x36 * 80 + sub * 16) = prei[k];
            }
        }
        __syncthreads();  // staging visible

#pragma unroll
        for (int gp = 0; gp < 5; ++gp) {
            fillA(true, icb, dz, gp, 1, bufB);
            compute(bufA, gp, 0);
            if (gp < 4) fillA(true, icb, dz, gp + 1, 0, bufA);
            else        fillA(more, nicb, ndz, 0, 0, bufA);
            if (gp == 0) { if (more) issue(nicb, ndz); }
            compute(bufB, gp, 1);
        }
    }

    __syncthreads();
    if (WRITE_H) {
        // bias + exact GELU, transpose to [x][oc] via LDS scratch (4 y-waves
        // x 32 x x 64 oc rows), store h[b][z][y][x][64] bf16.
#pragma unroll
        for (int j = 0; j < JT; ++j) {
            char* scr = lds_in + wy * (32 * 144);
#pragma unroll
            for (int r = 0; r < 16; ++r) {
                int ocr = (r & 3) + 8 * (r >> 2) + 4 * half;
                int oc = ochalf * 32 + ocr;
                float v = acc[j][r] + bias[oc];
                v = 0.5f * v * (1.f + erff(v * 0.70710678118654752f));
                *(unsigned short*)(scr + ln * 144 + oc * 2) = f2bf(v);
            }
            __syncthreads();
#pragma unroll
            for (int k = 0; k < 2; ++k) {
                int u = tid + 512 * k;          // 1024 = 4 wy * 32 x * 8 un
                int wyi = u >> 8, rem = u & 255;
                int xx = rem >> 3, un = rem & 7;
                uint4 v = *(const uint4*)(lds_in + wyi * (32 * 144) +
                                          xx * 144 + un * 16);
                int y = y0 + 4 * wyi + j;
                *(uint4*)(hout + ((((size_t)b * 32 + z) * 32 + y) * 32 + xx)
                          * 64 + un * 8) = v;
            }
            __syncthreads();
        }
    } else {
        // final: bias + attention (already alpha-scaled in fout) added in place
#pragma unroll
        for (int j = 0; j < JT; ++j) {
            int y = y0 + JT * wy + j;
#pragma unroll
            for (int r = 0; r < 16; ++r) {
                int oc = (r & 3) + 8 * (r >> 2) + 4 * half;
                size_t o = ((size_t)b * 32 + oc) * S3 + z * 1024 + y * 32 + ln;
                fout[o] = acc[j][r] + bias[oc] + fout[o];
            }
        }
    }
}

// ---------------------------------------------------------------------------
extern "C" void kernel_launch(void* const* d_in, const int* in_sizes, int n_in,
                              void* d_out, int out_size, void* d_ws, size_t ws_size,
                              hipStream_t stream)
{
    const float* x       = (const float*)d_in[0];
    const float* basis   = (const float*)d_in[1];
    const float* mixer   = (const float*)d_in[2];
    const float* wq      = (const float*)d_in[3];
    const float* wk      = (const float*)d_in[4];
    const float* wv      = (const float*)d_in[5];
    const float* conv1_w = (const float*)d_in[6];
    const float* conv1_b = (const float*)d_in[7];
    const float* conv2_w = (const float*)d_in[8];
    const float* conv2_b = (const float*)d_in[9];
    const float* alpha   = (const float*)d_in[10];
    float* out = (float*)d_out;

    char* wsb = (char*)d_ws;
    unsigned short* xb  = (unsigned short*)wsb;               // 32 MiB
    unsigned short* h   = (unsigned short*)(wsb + 33554432);  // 16 MiB
    // token/qbuf alias h: both dead before conv1 writes h (same stream order)
    float* token = (float*)(wsb + 33554432);                  // 4 MiB
    float* qbuf  = (float*)(wsb + 37748736);                  // 4 MiB
    unsigned short* wT1 = (unsigned short*)(wsb + 50331648);  // 2 MiB
    unsigned short* wT2 = (unsigned short*)(wsb + 52379648);  // 0.5 MiB

    wt_transpose<128, 64><<<4000, 256, 0, stream>>>(conv1_w, wT1);
    wt_transpose<64, 32><<<1000, 256, 0, stream>>>(conv2_w, wT2);
    xb_transpose<<<dim3(1024, 4), 256, 0, stream>>>(x, xb);

    token_q_kernel<<<S3 / 256, 256, 0, stream>>>(basis, mixer, wq, token, qbuf);
    attention_kernel<<<512, 256, 0, stream>>>(x, token, qbuf, wk, wv, alpha, out);

    conv_mfma<128, 64, true><<<dim3(32, 2, 4), 512, 0, stream>>>(
        xb, (const uint4*)wT1, conv1_b, h, nullptr);
    conv_mfma<64, 32, false><<<dim3(32, 2, 4), 512, 0, stream>>>(
        h, (const uint4*)wT2, conv2_b, nullptr, out);
}